// Round 8
// baseline (7780.279 us; speedup 1.0000x reference)
//
#include <hip/hip_runtime.h>
#include <math.h>

// KDC Lindblad propagator — real-basis reduction + fp64 MFMA + sparse Horner,
// persistent (grid-barrier) kernels for the Horner and chain phases.
// f64 16x16x4 C/D layout (HW-probed round 4): col=lane&15, row=(lane>>4)+4*reg.
// Pipeline: W = Taylor16(tau*T/8) via 16 sparse T-applies (one persistent
// kernel); U = W^8 (3 dense sq); V = U^32 (5 dense sq); transpose+chains+pops
// in one persistent kernel. 8 dgemms; 11 launches total.

#define DS 1024
#define MATD ((size_t)DS * DS * sizeof(double))
#define PA 66

typedef double v4d __attribute__((ext_vector_type(4)));

__device__ inline double Qel(int i, int j) {
    if (i == j + 1) return sqrt((double)i) * 0.70710678118654752440;
    if (j == i + 1) return sqrt((double)j) * 0.70710678118654752440;
    return 0.0;
}

__device__ inline void fill_H(double* Hs, int tid) {
    const double CM2EV = 0.00012398419;
    const double E_S1 = 3.995, E_S2 = 4.9183;
    const double om6a = 596.0 * CM2EV, om10a = 919.0 * CM2EV;
    const double kapA = -0.0964, kapB = 0.1193, lam = 0.1825, gam = -0.018;
    for (int h = tid; h < 1024; h += 256) {
        int r = h >> 5, c = h & 31;
        int e = r >> 4, v6 = (r >> 2) & 3, v10 = r & 3;
        int e2 = c >> 4, w6 = (c >> 2) & 3, w10 = c & 3;
        double val = 0.0;
        if (r == c) val += (e ? E_S2 : E_S1) + om6a * v6 + om10a * v10;
        if (e == e2 && v10 == w10) val += (e ? kapB : kapA) * Qel(v6, w6);
        if (e != e2 && v6 == w6) {
            double q2 = 0.0;
            #pragma unroll
            for (int m = 0; m < 4; ++m) q2 += Qel(v10, m) * Qel(m, w10);
            val += lam * Qel(v10, w10) + gam * q2;
        }
        Hs[h] = val;
    }
}

// ---- device-scope grid barrier (all blocks co-resident by construction) ----
__device__ inline void gridbar(unsigned* ctr, unsigned tgt)
{
    __threadfence();                 // publish my writes (agent scope: wb L2)
    __syncthreads();
    if (threadIdx.x == 0) {
        __hip_atomic_fetch_add(ctr, 1u, __ATOMIC_RELEASE,
                               __HIP_MEMORY_SCOPE_AGENT);
        while (__hip_atomic_load(ctr, __ATOMIC_ACQUIRE,
                                 __HIP_MEMORY_SCOPE_AGENT) < tgt)
            __builtin_amdgcn_s_sleep(8);
    }
    __syncthreads();
    __threadfence();                 // acquire: invalidate stale L1/L2 lines
}

// --------------------------------------------------------- horner (fused) ---
// G0 <- I; then 16 Horner steps G <- I + (tau/8/k) T G, alternating G0/G1.
// One block per output row p=(i,j); ends with W in G0.
__global__ __launch_bounds__(256)
void horner_fused(const float* __restrict__ logg, double* __restrict__ G0,
                  double* __restrict__ G1, unsigned* __restrict__ ctr)
{
    __shared__ double Hs[1024];
    const int tid = threadIdx.x;
    fill_H(Hs, tid);
    const double g = exp((double)logg[0]);
    const double tau8 = (1.0 / 0.6582119569) / 8.0;
    const int p = blockIdx.x;
    const int i = p >> 5, j = p & 31;
    const int NB = 1024;
    unsigned tgt = 0;

    // phase 0: identity
    int gid = blockIdx.x * 256 + tid;
    for (int q = gid; q < DS * DS; q += NB * 256)
        G0[q] = ((q >> 10) == (q & 1023)) ? 1.0 : 0.0;
    tgt += NB; gridbar(ctr, tgt);

    for (int k = 16; k >= 1; --k) {
        const double* M = (k & 1) ? G1 : G0;
        double*       O = (k & 1) ? G0 : G1;
        const double sck = tau8 / (double)k;
        double a0 = 0.0, a1 = 0.0, a2 = 0.0, a3 = 0.0;
        const int e = tid;

#define ADDROW(q, wgt) { const double* r_ = M + (size_t)(q) * DS; double w_ = (wgt); \
    a0 += w_ * r_[e]; a1 += w_ * r_[e + 256];                                        \
    a2 += w_ * r_[e + 512]; a3 += w_ * r_[e + 768]; }

        if (i <= j) {   // R-output row
            for (int m = 0; m < 32; ++m) {
                double c = Hs[i * 32 + m];
                if (c != 0.0 && m != j) {
                    if (m > j) ADDROW(m * 32 + j, -c)
                    else       ADDROW(j * 32 + m,  c)
                }
            }
            for (int m = 0; m < 32; ++m) {
                double c = Hs[m * 32 + j];
                if (c != 0.0 && m != i) {
                    if (i > m) ADDROW(i * 32 + m,  c)
                    else       ADDROW(m * 32 + i, -c)
                }
            }
            if (i < 16 && j < 16) ADDROW((i + 16) * 32 + (j + 16), g)
            if (i >= 16 || j >= 16)
                ADDROW(p, -0.5 * g * (double)((i >= 16) + (j >= 16)))
        } else {        // A-output row
            for (int m = 0; m < 32; ++m) {
                double c = Hs[i * 32 + m];
                if (c != 0.0) {
                    int lo = m < j ? m : j, hi = m < j ? j : m;
                    ADDROW(lo * 32 + hi, c)
                }
            }
            for (int m = 0; m < 32; ++m) {
                double c = Hs[m * 32 + j];
                if (c != 0.0) {
                    int lo = m < i ? m : i, hi = m < i ? i : m;
                    ADDROW(lo * 32 + hi, -c)
                }
            }
            if (i < 16 && j < 16) ADDROW((i + 16) * 32 + (j + 16), g)
            ADDROW(p, -0.5 * g * (double)((i >= 16) + (j >= 16)))
        }
#undef ADDROW

        size_t base = (size_t)p * DS;
        O[base + e]       = sck * a0 + ((p == e)       ? 1.0 : 0.0);
        O[base + e + 256] = sck * a1 + ((p == e + 256) ? 1.0 : 0.0);
        O[base + e + 512] = sck * a2 + ((p == e + 512) ? 1.0 : 0.0);
        O[base + e + 768] = sck * a3 + ((p == e + 768) ? 1.0 : 0.0);
        tgt += NB; gridbar(ctr, tgt);
    }
}

// --------------------------------------------------------- dgemm (MFMA f64) -
// D = A*B. 64x64 tile, 1024 threads (16 waves): 4 output quadrants x
// 4 k-groups (k-split-4 within KT=64); 3-phase LDS k-reduction.
// Round-5-proven operand pattern (PA=66, [row][k]/[k][col]), 4 waves/SIMD.
__global__ __launch_bounds__(1024, 1)
void dgemm(const double* __restrict__ A, const double* __restrict__ B,
           double* __restrict__ D)
{
    __shared__ double As[64 * PA];   // [row][k]
    __shared__ double Bs[64 * PA];   // [k][col]
    const int tid = threadIdx.x;
    const int bm = blockIdx.x << 6, bn = blockIdx.y << 6;
    const int w = tid >> 6, lane = tid & 63;
    const int lr = lane & 15, lk = lane >> 4;
    const int p = w & 3, kg = w >> 2;
    const int wr = (p >> 1) << 5, wc = (p & 1) << 5;

    v4d acc[2][2];
    #pragma unroll
    for (int si = 0; si < 2; ++si)
        #pragma unroll
        for (int sj = 0; sj < 2; ++sj) acc[si][sj] = (v4d){0., 0., 0., 0.};

    const int ra = tid >> 4;          // 0..63
    const int cs = (tid & 15) << 2;   // 0..60
    const double* gA = A + (size_t)(bm + ra) * DS + cs;
    const double* gB = B + (size_t)ra * DS + bn + cs;
    double va[4], vb[4];
    #pragma unroll
    for (int u = 0; u < 4; ++u) { va[u] = gA[u]; vb[u] = gB[u]; }

    for (int kt = 0; kt < DS; kt += 64) {
        #pragma unroll
        for (int u = 0; u < 4; ++u) {
            As[ra * PA + cs + u] = va[u];
            Bs[ra * PA + cs + u] = vb[u];
        }
        __syncthreads();
        if (kt + 64 < DS) {
            #pragma unroll
            for (int u = 0; u < 4; ++u) {
                va[u] = gA[kt + 64 + u];
                vb[u] = gB[(size_t)(kt + 64) * DS + u];
            }
        }
        #pragma unroll
        for (int s = 0; s < 4; ++s) {
            int k = (kg << 4) + (s << 2) + lk;
            double a0 = As[(wr + lr) * PA + k];
            double a1 = As[(wr + 16 + lr) * PA + k];
            double b0 = Bs[k * PA + wc + lr];
            double b1 = Bs[k * PA + wc + 16 + lr];
            acc[0][0] = __builtin_amdgcn_mfma_f64_16x16x4f64(a0, b0, acc[0][0], 0, 0, 0);
            acc[0][1] = __builtin_amdgcn_mfma_f64_16x16x4f64(a0, b1, acc[0][1], 0, 0, 0);
            acc[1][0] = __builtin_amdgcn_mfma_f64_16x16x4f64(a1, b0, acc[1][0], 0, 0, 0);
            acc[1][1] = __builtin_amdgcn_mfma_f64_16x16x4f64(a1, b1, acc[1][1], 0, 0, 0);
        }
        __syncthreads();
    }

    // k-split reduction: kg=3 writes red, kg=2,1 accumulate, kg=0 adds+stores.
    double* red = As;   // 64x64
    if (kg == 3) {
        #pragma unroll
        for (int si = 0; si < 2; ++si)
            #pragma unroll
            for (int sj = 0; sj < 2; ++sj)
                #pragma unroll
                for (int r = 0; r < 4; ++r)
                    red[(wr + si * 16 + lk + 4 * r) * 64 + wc + sj * 16 + lr]
                        = acc[si][sj][r];
    }
    __syncthreads();
    if (kg == 2) {
        #pragma unroll
        for (int si = 0; si < 2; ++si)
            #pragma unroll
            for (int sj = 0; sj < 2; ++sj)
                #pragma unroll
                for (int r = 0; r < 4; ++r)
                    red[(wr + si * 16 + lk + 4 * r) * 64 + wc + sj * 16 + lr]
                        += acc[si][sj][r];
    }
    __syncthreads();
    if (kg == 1) {
        #pragma unroll
        for (int si = 0; si < 2; ++si)
            #pragma unroll
            for (int sj = 0; sj < 2; ++sj)
                #pragma unroll
                for (int r = 0; r < 4; ++r)
                    red[(wr + si * 16 + lk + 4 * r) * 64 + wc + sj * 16 + lr]
                        += acc[si][sj][r];
    }
    __syncthreads();
    if (kg == 0) {
        #pragma unroll
        for (int si = 0; si < 2; ++si)
            #pragma unroll
            for (int sj = 0; sj < 2; ++sj) {
                int col = bn + wc + sj * 16 + lr;
                #pragma unroll
                for (int r = 0; r < 4; ++r) {
                    int row = bm + wr + si * 16 + lk + 4 * r;
                    D[(size_t)row * DS + col] = acc[si][sj][r]
                        + red[(wr + si * 16 + lk + 4 * r) * 64 + wc + sj * 16 + lr];
                }
            }
    }
}

// --------------------------------------------------------- chains (fused) ---
// Phase 0: UT = U^T (LDS-tiled), init Y/Z. Phases 1..31: chain steps.
// Tail: pops for t = 2*blk + (tid>>7). 512 blocks x 256 threads.
__global__ __launch_bounds__(256)
void chains_fused(const double* __restrict__ U, const double* __restrict__ V,
                  double* __restrict__ UT, double* __restrict__ Y,
                  double* __restrict__ Z, float* __restrict__ out, int n,
                  unsigned* __restrict__ ctr)
{
    __shared__ double tb[32][33];
    const int tid = threadIdx.x;
    const int NB = 512;
    unsigned tgt = 0;

    // ---- phase 0: transpose (2 tiles per block) + init ----
    #pragma unroll
    for (int rep = 0; rep < 2; ++rep) {
        int tt = blockIdx.x * 2 + rep;
        int bx = (tt & 31) << 5, by = (tt >> 5) << 5;
        int x = tid & 31, y = tid >> 5;
        #pragma unroll
        for (int dy = 0; dy < 32; dy += 8)
            tb[y + dy][x] = U[(size_t)(by + y + dy) * DS + bx + x];
        __syncthreads();
        #pragma unroll
        for (int dy = 0; dy < 32; dy += 8)
            UT[(size_t)(bx + y + dy) * DS + by + x] = tb[x][y + dy];
        __syncthreads();
    }
    int gid = blockIdx.x * 256 + tid;
    if (gid < 2048) {
        int k = gid >> 10, ii = gid & 1023;
        double v = 0.0;
        if (ii % 33 == 0) {
            int a = ii / 33;
            if ((a < 16) == (k == 0)) v = 1.0;
        }
        Y[gid] = v;
    } else if (gid < 3072) {
        Z[gid - 2048] = (gid == 2048 + 528) ? 1.0 : 0.0;
    }
    tgt += NB; gridbar(ctr, tgt);

    // ---- phases 1..31: chain steps ----
    const int gw = blockIdx.x * 4 + (tid >> 6);
    const int lane = tid & 63;
    for (int s = 1; s < 32; ++s) {
        const double* Yin = Y + (size_t)(s - 1) * 2048;
        double*       Yout = Y + (size_t)s * 2048;
        const double* Zin = Z + (size_t)(s - 1) * 1024;
        double*       Zout = Z + (size_t)s * 1024;
        if (gw < 1024) {
            const double* row = UT + (size_t)gw * DS;
            double s0 = 0.0, s1 = 0.0;
            for (int kk = lane; kk < DS; kk += 64) {
                double m = row[kk];
                s0 += m * Yin[kk];
                s1 += m * Yin[DS + kk];
            }
            #pragma unroll
            for (int off = 32; off; off >>= 1) {
                s0 += __shfl_down(s0, off);
                s1 += __shfl_down(s1, off);
            }
            if (lane == 0) { Yout[gw] = s0; Yout[DS + gw] = s1; }
        } else {
            int r = gw - 1024;
            const double* row = V + (size_t)r * DS;
            double sz = 0.0;
            for (int kk = lane; kk < DS; kk += 64) sz += row[kk] * Zin[kk];
            #pragma unroll
            for (int off = 32; off; off >>= 1) sz += __shfl_down(sz, off);
            if (lane == 0) Zout[r] = sz;
        }
        tgt += NB; gridbar(ctr, tgt);
    }

    // ---- tail: pops ----
    int t = blockIdx.x * 2 + (tid >> 7);
    int k = (tid >> 6) & 1;
    if (t < n) {
        int a = t & 31, j = t >> 5;
        const double* y = Y + (size_t)a * 2048 + (size_t)k * 1024;
        const double* z = Z + (size_t)j * 1024;
        double s = 0.0;
        for (int ii = lane; ii < 1024; ii += 64) s += y[ii] * z[ii];
        #pragma unroll
        for (int off = 32; off; off >>= 1) s += __shfl_down(s, off);
        if (lane == 0) {
            out[(size_t)(k + 1) * n + t] = (float)s;
            if (k == 0) out[t] = 0.0f;
        }
    }
}

// --------------------------------------------------------- host -------------
extern "C" void kernel_launch(void* const* d_in, const int* in_sizes, int n_in,
                              void* d_out, int out_size, void* d_ws, size_t ws_size,
                              hipStream_t stream)
{
    const float* logg = (const float*)d_in[0];
    float* out = (float*)d_out;
    const int n = out_size / 3;
    (void)in_sizes; (void)n_in; (void)ws_size;

    char* ws = (char*)d_ws;
    double* b0 = (double*)(ws + 0 * MATD);
    double* b1 = (double*)(ws + 1 * MATD);
    double* b2 = (double*)(ws + 2 * MATD);
    double* b3 = (double*)(ws + 3 * MATD);
    double* Y  = (double*)(ws + 4 * MATD);           // 32 x 2 x 1024
    double* Z  = Y + 32 * 2048;                      // 32 x 1024
    unsigned* ctrs = (unsigned*)(Z + 32 * 1024);     // 2 barrier counters

    hipMemsetAsync(ctrs, 0, 2 * sizeof(unsigned), stream);

    // W = Taylor16(tau*T/8) -> b0 (b1 scratch), one persistent launch
    horner_fused<<<1024, 256, 0, stream>>>(logg, b0, b1, ctrs + 0);

    // U = W^8 (3 sq), V = U^32 (5 sq)
    dim3 g2(16, 16);
    dgemm<<<g2, 1024, 0, stream>>>(b0, b0, b1);   // W^2
    dgemm<<<g2, 1024, 0, stream>>>(b1, b1, b2);   // W^4
    dgemm<<<g2, 1024, 0, stream>>>(b2, b2, b3);   // U = W^8
    dgemm<<<g2, 1024, 0, stream>>>(b3, b3, b1);   // U^2
    dgemm<<<g2, 1024, 0, stream>>>(b1, b1, b2);   // U^4
    dgemm<<<g2, 1024, 0, stream>>>(b2, b2, b1);   // U^8
    dgemm<<<g2, 1024, 0, stream>>>(b1, b1, b2);   // U^16
    dgemm<<<g2, 1024, 0, stream>>>(b2, b2, b1);   // V = U^32

    // transpose + chains + pops, one persistent launch (UT scratch in b2)
    chains_fused<<<512, 256, 0, stream>>>(b3, b1, b2, Y, Z, out, n, ctrs + 1);
}

// Round 9
// 865.954 us; speedup vs baseline: 8.9846x; 8.9846x over previous
//
#include <hip/hip_runtime.h>
#include <math.h>

// KDC Lindblad propagator — real-basis reduction + fp64 MFMA + sparse Horner.
// f64 16x16x4 C/D layout (HW-probed round 4): col=lane&15, row=(lane>>4)+4*reg.
//
// Round 9 = round-7 skeleton (919 us known-good; round-8 persistent-kernel
// grid barriers regressed 8.5x — agent-scope fences nuke per-XCD L2 locality)
// with two isolated changes:
//   (a) dgemm: 1024-thread / 16-wave k-split-4 variant (4 waves/SIMD stall
//       coverage; correctness-validated in round 8).
//   (b) Horner k=16 step folded into a direct dense build of I + (tau/128)T.
// Pipeline: G16 = I + (tau/8)/16 T (dense build); 15 sparse T-applies ->
// W = Taylor16(tau*T/8); U = W^8 (3 sq); V = U^32 (5 sq); meet-in-middle
// chains (t = a + 32 j); pops. 8 dense dgemms.

#define DS 1024
#define MATD ((size_t)DS * DS * sizeof(double))
#define PA 66

typedef double v4d __attribute__((ext_vector_type(4)));

__device__ inline double Qel(int i, int j) {
    if (i == j + 1) return sqrt((double)i) * 0.70710678118654752440;
    if (j == i + 1) return sqrt((double)j) * 0.70710678118654752440;
    return 0.0;
}

__device__ inline void fill_H(double* Hs, int tid) {
    const double CM2EV = 0.00012398419;
    const double E_S1 = 3.995, E_S2 = 4.9183;
    const double om6a = 596.0 * CM2EV, om10a = 919.0 * CM2EV;
    const double kapA = -0.0964, kapB = 0.1193, lam = 0.1825, gam = -0.018;
    for (int h = tid; h < 1024; h += 256) {
        int r = h >> 5, c = h & 31;
        int e = r >> 4, v6 = (r >> 2) & 3, v10 = r & 3;
        int e2 = c >> 4, w6 = (c >> 2) & 3, w10 = c & 3;
        double val = 0.0;
        if (r == c) val += (e ? E_S2 : E_S1) + om6a * v6 + om10a * v10;
        if (e == e2 && v10 == w10) val += (e ? kapB : kapA) * Qel(v6, w6);
        if (e != e2 && v6 == w6) {
            double q2 = 0.0;
            #pragma unroll
            for (int m = 0; m < 4; ++m) q2 += Qel(v10, m) * Qel(m, w10);
            val += lam * Qel(v10, w10) + gam * q2;
        }
        Hs[h] = val;
    }
}

// --------------------------------------------------------- build G16 --------
// G = I + sc*T  (sc = (tau/8)/16), dense entrywise (round-5-validated cases).
__global__ __launch_bounds__(256)
void build_G16(const float* __restrict__ logg, double* __restrict__ X)
{
    __shared__ double Hs[1024];
    int tid = threadIdx.x;
    fill_H(Hs, tid);
    __syncthreads();
    double g = exp((double)logg[0]);
    const double sc = ((1.0 / 0.6582119569) / 8.0) / 16.0;
    int idx = blockIdx.x * 256 + tid;
    int r = idx >> 10, c = idx & 1023;
    int i = r >> 5, j = r & 31;
    int k = c >> 5, l = c & 31;
    double t = 0.0;
    if (k <= l) {                  // R basis
        if (i <= j) {              // R row: dissipator only
            if (i < 16 && j < 16) {
                int p = i + 16, q = j + 16;
                if ((p == k && q == l) || (p == l && q == k)) t += g;
            }
            if (i == k && j == l) t -= 0.5 * g * ((i >= 16) + (j >= 16));
        } else {                   // A row: [H,R][i,j]
            if (j == l) t += Hs[i * 32 + k];
            if (k != l && j == k) t += Hs[i * 32 + l];
            if (i == k) t -= Hs[l * 32 + j];
            if (k != l && i == l) t -= Hs[k * 32 + j];
        }
    } else {                       // A basis (k>l)
        if (i <= j) {              // R row: -[H,A][i,j]
            double ha = 0.0;
            if (j == l) ha += Hs[i * 32 + k];
            if (j == k) ha -= Hs[i * 32 + l];
            if (i == k) ha -= Hs[l * 32 + j];
            if (i == l) ha += Hs[k * 32 + j];
            t -= ha;
        } else {                   // A row: dissipator
            if (i < 16 && j < 16 && (i + 16 == k) && (j + 16 == l)) t += g;
            if (i == k && j == l) t -= 0.5 * g * ((i >= 16) + (j >= 16));
        }
    }
    X[idx] = t * sc + ((r == c) ? 1.0 : 0.0);
}

// --------------------------------------------------------- sparse T-apply ---
// O = I + sck * (T @ M), sck = (DT/HBAR)/8 / k  (Horner step).
__global__ __launch_bounds__(256)
void apply_T(const float* __restrict__ logg, const double* __restrict__ M,
             double* __restrict__ O, double invk)
{
    __shared__ double Hs[1024];
    const int tid = threadIdx.x;
    fill_H(Hs, tid);
    __syncthreads();
    const double g = exp((double)logg[0]);
    const double sck = ((1.0 / 0.6582119569) / 8.0) * invk;
    const int p = blockIdx.x;
    const int i = p >> 5, j = p & 31;

    double a0 = 0.0, a1 = 0.0, a2 = 0.0, a3 = 0.0;
    const int e = tid;

#define ADDROW(q, wgt) { const double* r_ = M + (size_t)(q) * DS; double w_ = (wgt); \
    a0 += w_ * r_[e]; a1 += w_ * r_[e + 256];                                        \
    a2 += w_ * r_[e + 512]; a3 += w_ * r_[e + 768]; }

    if (i <= j) {   // R-output row
        for (int m = 0; m < 32; ++m) {
            double c = Hs[i * 32 + m];
            if (c != 0.0 && m != j) {
                if (m > j) ADDROW(m * 32 + j, -c)
                else       ADDROW(j * 32 + m,  c)
            }
        }
        for (int m = 0; m < 32; ++m) {
            double c = Hs[m * 32 + j];
            if (c != 0.0 && m != i) {
                if (i > m) ADDROW(i * 32 + m,  c)
                else       ADDROW(m * 32 + i, -c)
            }
        }
        if (i < 16 && j < 16) ADDROW((i + 16) * 32 + (j + 16), g)
        if (i >= 16 || j >= 16)
            ADDROW(p, -0.5 * g * (double)((i >= 16) + (j >= 16)))
    } else {        // A-output row
        for (int m = 0; m < 32; ++m) {
            double c = Hs[i * 32 + m];
            if (c != 0.0) {
                int lo = m < j ? m : j, hi = m < j ? j : m;
                ADDROW(lo * 32 + hi, c)
            }
        }
        for (int m = 0; m < 32; ++m) {
            double c = Hs[m * 32 + j];
            if (c != 0.0) {
                int lo = m < i ? m : i, hi = m < i ? i : m;
                ADDROW(lo * 32 + hi, -c)
            }
        }
        if (i < 16 && j < 16) ADDROW((i + 16) * 32 + (j + 16), g)
        ADDROW(p, -0.5 * g * (double)((i >= 16) + (j >= 16)))
    }
#undef ADDROW

    size_t base = (size_t)p * DS;
    O[base + e]       = sck * a0 + ((p == e)       ? 1.0 : 0.0);
    O[base + e + 256] = sck * a1 + ((p == e + 256) ? 1.0 : 0.0);
    O[base + e + 512] = sck * a2 + ((p == e + 512) ? 1.0 : 0.0);
    O[base + e + 768] = sck * a3 + ((p == e + 768) ? 1.0 : 0.0);
}

// --------------------------------------------------------- dgemm (MFMA f64) -
// D = A*B. 64x64 tile, 1024 threads (16 waves): 4 output quadrants x
// 4 k-groups (k-split-4 within KT=64); 3-phase LDS k-reduction.
// Correctness-validated round 8; speed isolated this round.
__global__ __launch_bounds__(1024, 1)
void dgemm(const double* __restrict__ A, const double* __restrict__ B,
           double* __restrict__ D)
{
    __shared__ double As[64 * PA];   // [row][k]
    __shared__ double Bs[64 * PA];   // [k][col]
    const int tid = threadIdx.x;
    const int bm = blockIdx.x << 6, bn = blockIdx.y << 6;
    const int w = tid >> 6, lane = tid & 63;
    const int lr = lane & 15, lk = lane >> 4;
    const int p = w & 3, kg = w >> 2;
    const int wr = (p >> 1) << 5, wc = (p & 1) << 5;

    v4d acc[2][2];
    #pragma unroll
    for (int si = 0; si < 2; ++si)
        #pragma unroll
        for (int sj = 0; sj < 2; ++sj) acc[si][sj] = (v4d){0., 0., 0., 0.};

    const int ra = tid >> 4;          // 0..63
    const int cs = (tid & 15) << 2;   // 0..60
    const double* gA = A + (size_t)(bm + ra) * DS + cs;
    const double* gB = B + (size_t)ra * DS + bn + cs;
    double va[4], vb[4];
    #pragma unroll
    for (int u = 0; u < 4; ++u) { va[u] = gA[u]; vb[u] = gB[u]; }

    for (int kt = 0; kt < DS; kt += 64) {
        #pragma unroll
        for (int u = 0; u < 4; ++u) {
            As[ra * PA + cs + u] = va[u];
            Bs[ra * PA + cs + u] = vb[u];
        }
        __syncthreads();
        if (kt + 64 < DS) {
            #pragma unroll
            for (int u = 0; u < 4; ++u) {
                va[u] = gA[kt + 64 + u];
                vb[u] = gB[(size_t)(kt + 64) * DS + u];
            }
        }
        #pragma unroll
        for (int s = 0; s < 4; ++s) {
            int k = (kg << 4) + (s << 2) + lk;
            double a0 = As[(wr + lr) * PA + k];
            double a1 = As[(wr + 16 + lr) * PA + k];
            double b0 = Bs[k * PA + wc + lr];
            double b1 = Bs[k * PA + wc + 16 + lr];
            acc[0][0] = __builtin_amdgcn_mfma_f64_16x16x4f64(a0, b0, acc[0][0], 0, 0, 0);
            acc[0][1] = __builtin_amdgcn_mfma_f64_16x16x4f64(a0, b1, acc[0][1], 0, 0, 0);
            acc[1][0] = __builtin_amdgcn_mfma_f64_16x16x4f64(a1, b0, acc[1][0], 0, 0, 0);
            acc[1][1] = __builtin_amdgcn_mfma_f64_16x16x4f64(a1, b1, acc[1][1], 0, 0, 0);
        }
        __syncthreads();
    }

    double* red = As;   // 64x64
    if (kg == 3) {
        #pragma unroll
        for (int si = 0; si < 2; ++si)
            #pragma unroll
            for (int sj = 0; sj < 2; ++sj)
                #pragma unroll
                for (int r = 0; r < 4; ++r)
                    red[(wr + si * 16 + lk + 4 * r) * 64 + wc + sj * 16 + lr]
                        = acc[si][sj][r];
    }
    __syncthreads();
    if (kg == 2) {
        #pragma unroll
        for (int si = 0; si < 2; ++si)
            #pragma unroll
            for (int sj = 0; sj < 2; ++sj)
                #pragma unroll
                for (int r = 0; r < 4; ++r)
                    red[(wr + si * 16 + lk + 4 * r) * 64 + wc + sj * 16 + lr]
                        += acc[si][sj][r];
    }
    __syncthreads();
    if (kg == 1) {
        #pragma unroll
        for (int si = 0; si < 2; ++si)
            #pragma unroll
            for (int sj = 0; sj < 2; ++sj)
                #pragma unroll
                for (int r = 0; r < 4; ++r)
                    red[(wr + si * 16 + lk + 4 * r) * 64 + wc + sj * 16 + lr]
                        += acc[si][sj][r];
    }
    __syncthreads();
    if (kg == 0) {
        #pragma unroll
        for (int si = 0; si < 2; ++si)
            #pragma unroll
            for (int sj = 0; sj < 2; ++sj) {
                int col = bn + wc + sj * 16 + lr;
                #pragma unroll
                for (int r = 0; r < 4; ++r) {
                    int row = bm + wr + si * 16 + lk + 4 * r;
                    D[(size_t)row * DS + col] = acc[si][sj][r]
                        + red[(wr + si * 16 + lk + 4 * r) * 64 + wc + sj * 16 + lr];
                }
            }
    }
}

// --------------------------------------------------------- transpose --------
__global__ __launch_bounds__(256)
void transposeK(const double* __restrict__ M, double* __restrict__ MT)
{
    __shared__ double t[32][33];
    int bx = blockIdx.x << 5, by = blockIdx.y << 5;
    int x = threadIdx.x & 31, y = threadIdx.x >> 5;
    #pragma unroll
    for (int dy = 0; dy < 32; dy += 8)
        t[y + dy][x] = M[(size_t)(by + y + dy) * DS + bx + x];
    __syncthreads();
    #pragma unroll
    for (int dy = 0; dy < 32; dy += 8)
        MT[(size_t)(bx + y + dy) * DS + by + x] = t[x][y + dy];
}

// --------------------------------------------------------- chains -----------
__global__ __launch_bounds__(256)
void init_chains(double* __restrict__ Y, double* __restrict__ Z)
{
    int idx = blockIdx.x * 256 + threadIdx.x;
    if (idx < 2048) {
        int k = idx >> 10, i = idx & 1023;
        double v = 0.0;
        if (i % 33 == 0) {
            int a = i / 33;
            if ((a < 16) == (k == 0)) v = 1.0;
        }
        Y[idx] = v;
    } else if (idx < 3072) {
        int i = idx - 2048;
        Z[i] = (i == 528) ? 1.0 : 0.0;
    }
}

__global__ __launch_bounds__(256)
void chain_step(const double* __restrict__ UT, const double* __restrict__ V,
                const double* __restrict__ Yin, double* __restrict__ Yout,
                const double* __restrict__ Zin, double* __restrict__ Zout)
{
    int gw = blockIdx.x * 4 + (threadIdx.x >> 6);
    int lane = threadIdx.x & 63;
    if (gw < 1024) {
        const double* row = UT + (size_t)gw * DS;
        double s0 = 0.0, s1 = 0.0;
        for (int kk = lane; kk < DS; kk += 64) {
            double m = row[kk];
            s0 += m * Yin[kk];
            s1 += m * Yin[DS + kk];
        }
        #pragma unroll
        for (int off = 32; off; off >>= 1) {
            s0 += __shfl_down(s0, off);
            s1 += __shfl_down(s1, off);
        }
        if (lane == 0) { Yout[gw] = s0; Yout[DS + gw] = s1; }
    } else {
        int r = gw - 1024;
        const double* row = V + (size_t)r * DS;
        double s = 0.0;
        for (int kk = lane; kk < DS; kk += 64) s += row[kk] * Zin[kk];
        #pragma unroll
        for (int off = 32; off; off >>= 1) s += __shfl_down(s, off);
        if (lane == 0) Zout[r] = s;
    }
}

// --------------------------------------------------------- output -----------
__global__ __launch_bounds__(128)
void final_pops(const double* __restrict__ Y, const double* __restrict__ Z,
                float* __restrict__ out, int n)
{
    int t = blockIdx.x;
    int k = threadIdx.x >> 6, lane = threadIdx.x & 63;
    int a = t & 31, j = t >> 5;
    const double* y = Y + (size_t)a * 2048 + (size_t)k * 1024;
    const double* z = Z + (size_t)j * 1024;
    double s = 0.0;
    for (int i = lane; i < 1024; i += 64) s += y[i] * z[i];
    #pragma unroll
    for (int off = 32; off; off >>= 1) s += __shfl_down(s, off);
    if (lane == 0) {
        out[(size_t)(k + 1) * n + t] = (float)s;
        if (k == 0) out[t] = 0.0f;
    }
}

// --------------------------------------------------------- host -------------
extern "C" void kernel_launch(void* const* d_in, const int* in_sizes, int n_in,
                              void* d_out, int out_size, void* d_ws, size_t ws_size,
                              hipStream_t stream)
{
    const float* logg = (const float*)d_in[0];
    float* out = (float*)d_out;
    const int n = out_size / 3;
    (void)in_sizes; (void)n_in; (void)ws_size;

    char* ws = (char*)d_ws;
    double* b0 = (double*)(ws + 0 * MATD);
    double* b1 = (double*)(ws + 1 * MATD);
    double* b2 = (double*)(ws + 2 * MATD);
    double* b3 = (double*)(ws + 3 * MATD);
    double* Y  = (double*)(ws + 4 * MATD);   // 32 x 2 x 1024
    double* Z  = Y + 32 * 2048;              // 32 x 1024

    dim3 g2(16, 16);

    // ---- W = Taylor16(tau*T/8): G16 = I + X/16 (dense), then 15 applies ----
    build_G16<<<4096, 256, 0, stream>>>(logg, b0);
    double* src = b0; double* dst = b1;
    for (int k = 15; k >= 1; --k) {
        apply_T<<<1024, 256, 0, stream>>>(logg, src, dst, 1.0 / (double)k);
        double* t = src; src = dst; dst = t;
    }
    // 15 applies (odd) -> W in b1
    // ---- U = W^8 (3 sq), V = U^32 (5 sq) ----
    dgemm<<<g2, 1024, 0, stream>>>(b1, b1, b2);   // W^2
    dgemm<<<g2, 1024, 0, stream>>>(b2, b2, b0);   // W^4
    dgemm<<<g2, 1024, 0, stream>>>(b0, b0, b3);   // U = W^8
    dgemm<<<g2, 1024, 0, stream>>>(b3, b3, b0);   // U^2
    dgemm<<<g2, 1024, 0, stream>>>(b0, b0, b2);   // U^4
    dgemm<<<g2, 1024, 0, stream>>>(b2, b2, b0);   // U^8
    dgemm<<<g2, 1024, 0, stream>>>(b0, b0, b2);   // U^16
    dgemm<<<g2, 1024, 0, stream>>>(b2, b2, b1);   // V = U^32

    // ---- chains ----
    transposeK<<<dim3(32, 32), 256, 0, stream>>>(b3, b0);              // UT
    init_chains<<<12, 256, 0, stream>>>(Y, Z);
    for (int a = 1; a < 32; ++a)
        chain_step<<<512, 256, 0, stream>>>(b0, b1,
            Y + (size_t)(a - 1) * 2048, Y + (size_t)a * 2048,
            Z + (size_t)(a - 1) * 1024, Z + (size_t)a * 1024);
    final_pops<<<n, 128, 0, stream>>>(Y, Z, out, n);
}